// Round 7
// baseline (1783.995 us; speedup 1.0000x reference)
//
#include <hip/hip_runtime.h>
#include <math.h>

#define NB 8
#define C2 512
#define C3 1024
#define HIN2 28
#define HIN3 14
#define HO2 27
#define HO3 13
#define CC 1536
#define NP (NB*HO2*HO2)   /* 5832 */
#define NM 32000
#define NKNN 9
#define OH 224
#define AMAP_N (NB*OH*OH) /* 401408 */

/* 256x256 tile GEMM geometry */
#define BM 256
#define BN 256
#define BK 64
#define KT (CC/BK)        /* 24 */
#define MB_CNT ((NP+BM-1)/BM)   /* 23 */
#define NB_CNT (NM/BN)          /* 125 */
#define NWG (MB_CNT*NB_CNT)     /* 2875 */

typedef unsigned long long u64;
typedef unsigned int u32;
typedef __attribute__((ext_vector_type(8))) short bf16x8;
typedef __attribute__((ext_vector_type(4))) float f32x4;

struct GW { float w[33]; };

__device__ __forceinline__ float warp_sum(float v){
  #pragma unroll
  for (int off=32; off; off>>=1) v += __shfl_down(v, off);
  return v;
}

__device__ __forceinline__ ushort f2bf(float f){
  u32 u = __float_as_uint(f);
  u32 r = (u + 0x7FFFu + ((u>>16)&1u)) >> 16;
  return (ushort)r;
}
__device__ __forceinline__ float bf2f(ushort b){
  return __uint_as_float(((u32)b)<<16);
}

#define GLDS(g, l) __builtin_amdgcn_global_load_lds((const __attribute__((address_space(1))) void*)(g), (__attribute__((address_space(3))) void*)(l), 16, 0, 0)
#define WAITVM16() asm volatile("s_waitcnt vmcnt(16)" ::: "memory")
#define WAITVM0() asm volatile("s_waitcnt vmcnt(0)" ::: "memory")
#define SB0() __builtin_amdgcn_sched_barrier(0)
__device__ __forceinline__ void bar_raw(){
  asm volatile("" ::: "memory");
  __builtin_amdgcn_s_barrier();
  asm volatile("" ::: "memory");
}

// ---------------- avg pool k=4,s=1,p=1 (LDS-tiled transpose), write bf16 emb ----------------
__global__ __launch_bounds__(256) void k_avgpool2(const float* __restrict__ in, ushort* __restrict__ embB){
  __shared__ float pl[16*789];
  int b = blockIdx.x >> 5, cg = blockIdx.x & 31;
  const float4* src = (const float4*)(in + ((size_t)b*C2 + cg*16)*(HIN2*HIN2));
  for (int idx = threadIdx.x; idx < 16*196; idx += 256){
    int c = idx/196, p4 = idx - c*196;
    float4 v = src[idx];
    float* d = &pl[c*789 + p4*4];
    d[0]=v.x; d[1]=v.y; d[2]=v.z; d[3]=v.w;
  }
  __syncthreads();
  int c = threadIdx.x & 15, g = threadIdx.x >> 4;
  for (int pos = g; pos < HO2*HO2; pos += 16){
    int i = pos/HO2, j = pos - i*HO2;
    const float* p = &pl[c*789];
    float s = 0.f;
    #pragma unroll
    for (int di=0; di<4; ++di){
      int y = i - 1 + di;
      if ((unsigned)y >= HIN2) continue;
      #pragma unroll
      for (int dj=0; dj<4; ++dj){
        int x = j - 1 + dj;
        if ((unsigned)x < HIN2) s += p[y*HIN2 + x];
      }
    }
    embB[((size_t)((b*HO2 + i)*HO2 + j))*CC + cg*16 + c] = f2bf(s * (1.f/16.f));
  }
}

__global__ __launch_bounds__(256) void k_avgpool3(const float* __restrict__ in, float* __restrict__ f3p){
  __shared__ float pl[64*197];
  int b = blockIdx.x >> 4, cg = blockIdx.x & 15;
  const float4* src = (const float4*)(in + ((size_t)b*C3 + cg*64)*(HIN3*HIN3));
  for (int idx = threadIdx.x; idx < 64*49; idx += 256){
    int c = idx/49, p4 = idx - c*49;
    float4 v = src[idx];
    float* d = &pl[c*197 + p4*4];
    d[0]=v.x; d[1]=v.y; d[2]=v.z; d[3]=v.w;
  }
  __syncthreads();
  int c = threadIdx.x & 63, g = threadIdx.x >> 6;
  for (int pos = g; pos < HO3*HO3; pos += 4){
    int i = pos/HO3, j = pos - i*HO3;
    const float* p = &pl[c*197];
    float s = 0.f;
    #pragma unroll
    for (int di=0; di<4; ++di){
      int y = i - 1 + di;
      if ((unsigned)y >= HIN3) continue;
      #pragma unroll
      for (int dj=0; dj<4; ++dj){
        int x = j - 1 + dj;
        if ((unsigned)x < HIN3) s += p[y*HIN3 + x];
      }
    }
    f3p[((size_t)((b*HO3 + i)*HO3 + j))*C3 + cg*64 + c] = s * (1.f/16.f);
  }
}

// ---------------- bilinear 13x13 -> 27x27 (half-pixel, clamp), write bf16 ----------------
__global__ void k_upsample3(const float* __restrict__ f3p, ushort* __restrict__ embB){
  int t = blockIdx.x*256 + threadIdx.x;
  if (t >= NB*HO2*HO2*C3) return;
  int c = t % C3; int r = t / C3;
  int ox = r % HO2; r /= HO2;
  int oy = r % HO2; int b = r / HO2;
  float fy = (oy + 0.5f) * (13.f/27.f) - 0.5f;
  float fx = (ox + 0.5f) * (13.f/27.f) - 0.5f;
  int y0 = (int)floorf(fy); float wy = fy - (float)y0;
  int x0 = (int)floorf(fx); float wx = fx - (float)x0;
  int y0c = min(max(y0,0), HO3-1), y1c = min(max(y0+1,0), HO3-1);
  int x0c = min(max(x0,0), HO3-1), x1c = min(max(x0+1,0), HO3-1);
  const float* base = f3p + (size_t)(b*HO3*HO3)*C3;
  float v00 = base[(size_t)(y0c*HO3 + x0c)*C3 + c];
  float v01 = base[(size_t)(y0c*HO3 + x1c)*C3 + c];
  float v10 = base[(size_t)(y1c*HO3 + x0c)*C3 + c];
  float v11 = base[(size_t)(y1c*HO3 + x1c)*C3 + c];
  float v = (1.f-wy)*((1.f-wx)*v00 + wx*v01) + wy*((1.f-wx)*v10 + wx*v11);
  embB[((size_t)((b*HO2 + oy)*HO2 + ox))*CC + C2 + c] = f2bf(v);
}

// ---------------- fused bank fp32->bf16 convert + row sum of squares ----------------
__global__ void k_bank_prep(const float* __restrict__ bank, ushort* __restrict__ bankB,
                            float* __restrict__ y2){
  int wave = threadIdx.x >> 6, lane = threadIdx.x & 63;
  int r = blockIdx.x*4 + wave;
  if (r >= NM) return;
  const float4* p = (const float4*)(bank + (size_t)r*CC);
  ushort4* q = (ushort4*)(bankB + (size_t)r*CC);
  float s = 0.f;
  #pragma unroll
  for (int it=0; it<6; ++it){
    float4 v = p[it*64 + lane];
    s += v.x*v.x + v.y*v.y + v.z*v.z + v.w*v.w;
    ushort4 o; o.x = f2bf(v.x); o.y = f2bf(v.y); o.z = f2bf(v.z); o.w = f2bf(v.w);
    q[it*64 + lane] = o;
  }
  s = warp_sum(s);
  if (lane==0) y2[r] = s;
}

// also initializes packed[] (rows == NP)
__global__ void k_rowsumsq_bf(const ushort* __restrict__ src, float* __restrict__ dst, int rows,
                              u64* __restrict__ packed){
  int wave = threadIdx.x >> 6;
  int lane = threadIdx.x & 63;
  int r = blockIdx.x*4 + wave;
  if (r >= rows) return;
  const uint4* p = (const uint4*)(src + (size_t)r*CC);
  float s = 0.f;
  #pragma unroll
  for (int it=0; it<3; ++it){
    uint4 v = p[it*64 + lane];
    u32 ws_[4] = {v.x, v.y, v.z, v.w};
    #pragma unroll
    for (int q=0;q<4;q++){
      float lo = __uint_as_float(ws_[q]<<16);
      float hi = __uint_as_float(ws_[q]&0xFFFF0000u);
      s += lo*lo + hi*hi;
    }
  }
  s = warp_sum(s);
  if (lane==0){ dst[r] = s; packed[r] = ~0ull; }
}

// ---------------- fused bf16 MFMA distance GEMM + min/argmin ----------------
// A-direct: A fragments load global->VGPR (contiguous 16B/lane, L1/L2-hot; nb-fastest
// block order keeps the A panel resident). LDS holds only B (64KB dbuf, XOR-swizzled).
// LDS traffic/K-tile drops 256KB -> 96KB (<< MFMA 2480cy). One barrier per K-tile;
// vmcnt(16) retires only the 4 B-stage GLDS, 16 A-prefetch loads stay in flight.
__global__ __launch_bounds__(512, 2) void k_distmin_mfma(
    const ushort* __restrict__ A, const ushort* __restrict__ B,
    const float* __restrict__ x2, const float* __restrict__ y2,
    u64* __restrict__ packed)
{
  __shared__ ushort smem[2*BN*BK];   // [B0 | B1] = 64KB
  ushort* Bs0 = smem;
  ushort* Bs1 = smem + BN*BK;

  const int tid = threadIdx.x;
  const int w   = tid >> 6;          // wave 0..7
  const int l   = tid & 63;
  const int wr  = w >> 2;            // 0..1  (M: wr*128)
  const int wc  = w & 3;             // 0..3  (N: wc*64)
  const int ccol = l & 15;
  const int cgrp = l >> 4;

  // bijective XCD swizzle (m204); nb FASTEST so consecutive blocks share the A panel
  int orig = blockIdx.x;
  const int q8 = NWG/8, r8 = NWG%8;
  int xcd = orig & 7, sidx = orig >> 3;
  int wg = (xcd < r8 ? xcd*(q8+1) : r8*(q8+1) + (xcd-r8)*q8) + sidx;
  const int nb = wg % NB_CNT;
  const int mb = wg / NB_CNT;
  const int m0 = mb * BM;
  const int n0 = nb * BN;

  // B staging: 32 chunks of 8 rows x 64 cols; wave w owns chunks w*4..w*4+3
  const int rowin = l >> 3;
  const int scol  = (((l&7) ^ rowin) * 8);     // swizzled source segment (T2)
  u32 bOff[4]; u32 lOff[4];
  #pragma unroll
  for (int c=0;c<4;c++){
    int chunk = w*4 + c;
    bOff[c] = (u32)(n0 + chunk*8 + rowin)*CC + scol;
    lOff[c] = (u32)chunk*1024 + l*16;
  }

  // A fragment global element offsets (k-part folded: + cgrp*8)
  u32 aOff[8];
  #pragma unroll
  for (int mi=0;mi<8;mi++)
    aOff[mi] = (u32)min(m0 + wr*128 + mi*16 + ccol, NP-1)*CC + cgrp*8;

  // B fragment LDS read bases
  const u32 o0 = (u32)((cgrp ^ (ccol & 7)) * 8);
  u32 bRow[4];
  #pragma unroll
  for (int ni=0;ni<4;ni++) bRow[ni] = (u32)(wc*64 + ni*16 + ccol)*BK;

  f32x4 acc[8][4];
  #pragma unroll
  for (int mi=0;mi<8;mi++)
    #pragma unroll
    for (int ni=0;ni<4;ni++)
      acc[mi][ni] = (f32x4){0.f,0.f,0.f,0.f};

  bf16x8 aF[8][2], bF[4][2];

  // -------- prologue: stage B(0), load A(0) --------
  #pragma unroll
  for (int c=0;c<4;c++) GLDS(B + bOff[c], (char*)Bs0 + lOff[c]);
  #pragma unroll
  for (int mi=0;mi<8;mi++)
    #pragma unroll
    for (int ks=0;ks<2;ks++)
      aF[mi][ks] = *(const bf16x8*)(A + aOff[mi] + ks*32);
  #pragma unroll
  for (int mi=0;mi<8;mi++) aOff[mi] += 64;
  WAITVM0(); bar_raw(); SB0();

  const ushort* cB = Bs0; ushort* nB = Bs1;

  #pragma unroll 1
  for (int kt=0; kt<KT; ++kt){
    // B fragment reads for this tile (conflict-free via T2 swizzle)
    #pragma unroll
    for (int ni=0;ni<4;ni++)
      #pragma unroll
      for (int ks=0;ks<2;ks++)
        bF[ni][ks] = *(const bf16x8*)&cB[bRow[ni] + (o0 ^ (u32)(ks<<5))];

    // stage next B k-tile (the 4 oldest VMEM ops of this tile)
    #pragma unroll
    for (int c=0;c<4;c++) bOff[c] += 64;
    #pragma unroll
    for (int c=0;c<4;c++) GLDS(B + bOff[c], (char*)nB + lOff[c]);
    SB0();   // pin: GLDS issued before the A prefetch loads below

    // first half: mi 0..3
    __builtin_amdgcn_s_setprio(1);
    #pragma unroll
    for (int mi=0;mi<4;mi++)
      #pragma unroll
      for (int ni=0;ni<4;ni++)
        #pragma unroll
        for (int ks=0;ks<2;ks++)
          acc[mi][ni] = __builtin_amdgcn_mfma_f32_16x16x32_bf16(aF[mi][ks], bF[ni][ks], acc[mi][ni], 0, 0, 0);
    __builtin_amdgcn_s_setprio(0);

    // prefetch A-lo(next) into the now-dead aF[0..3]
    #pragma unroll
    for (int mi=0;mi<4;mi++)
      #pragma unroll
      for (int ks=0;ks<2;ks++)
        aF[mi][ks] = *(const bf16x8*)(A + aOff[mi] + ks*32);

    // second half: mi 4..7
    __builtin_amdgcn_s_setprio(1);
    #pragma unroll
    for (int mi=4;mi<8;mi++)
      #pragma unroll
      for (int ni=0;ni<4;ni++)
        #pragma unroll
        for (int ks=0;ks<2;ks++)
          acc[mi][ni] = __builtin_amdgcn_mfma_f32_16x16x32_bf16(aF[mi][ks], bF[ni][ks], acc[mi][ni], 0, 0, 0);
    __builtin_amdgcn_s_setprio(0);

    // prefetch A-hi(next)
    #pragma unroll
    for (int mi=4;mi<8;mi++)
      #pragma unroll
      for (int ks=0;ks<2;ks++)
        aF[mi][ks] = *(const bf16x8*)(A + aOff[mi] + ks*32);
    #pragma unroll
    for (int mi=0;mi<8;mi++) aOff[mi] += 64;

    WAITVM16();   // retire the 4 GLDS (oldest); 16 A loads stay in flight
    bar_raw(); SB0();
    ushort* t = (ushort*)cB; cB = nB; nB = t;
  }
  WAITVM0();   // drain tail garbage loads

  // epilogue: d2 = x2 + y2 - 2*dot ; min over this block's 256 columns, then atomicMin
  float xv[8][4];
  #pragma unroll
  for (int mi=0;mi<8;mi++)
    #pragma unroll
    for (int r=0;r<4;r++)
      xv[mi][r] = x2[min(m0 + wr*128 + mi*16 + cgrp*4 + r, NP-1)];

  u64 best[8][4];
  #pragma unroll
  for (int mi=0;mi<8;mi++)
    #pragma unroll
    for (int r=0;r<4;r++) best[mi][r] = ~0ull;

  #pragma unroll
  for (int ni=0;ni<4;ni++){
    const int n = n0 + wc*64 + ni*16 + ccol;
    const float yy = y2[n];
    #pragma unroll
    for (int mi=0;mi<8;mi++)
      #pragma unroll
      for (int r=0;r<4;r++){
        float d2 = fmaxf(xv[mi][r] + yy - 2.f*acc[mi][ni][r], 0.f);
        u64 pk = (((u64)__float_as_uint(d2))<<32) | (u32)n;
        if (pk < best[mi][r]) best[mi][r] = pk;
      }
  }

  #pragma unroll
  for (int mi=0;mi<8;mi++)
    #pragma unroll
    for (int r=0;r<4;r++){
      u64 pk = best[mi][r];
      #pragma unroll
      for (int md=1; md<16; md<<=1){
        u64 o = __shfl_xor(pk, md);
        if (o < pk) pk = o;
      }
      const int row = m0 + wr*128 + mi*16 + cgrp*4 + r;
      if (ccol==0 && row < NP) atomicMin(&packed[row], pk);
    }
}

__global__ void k_unpack(const u64* __restrict__ packed, float* __restrict__ patch_d, int* __restrict__ loc){
  int t = blockIdx.x*256 + threadIdx.x;
  if (t < NP){
    u64 v = packed[t];
    patch_d[t] = sqrtf(__uint_as_float((u32)(v>>32)));
    loc[t] = (int)(v & 0xffffffffu);
  }
}

// ---------------- per-batch argmax of patch scores ----------------
__global__ void k_argmax(const float* __restrict__ patch_d, const int* __restrict__ loc,
                         int* __restrict__ sel_mp, float* __restrict__ sel_score, int* __restrict__ sel_nn){
  int b = blockIdx.x;
  int tid = threadIdx.x;
  __shared__ u64 red[4];
  u64 best = 0;
  for (int p = tid; p < HO2*HO2; p += 256){
    float v = patch_d[b*HO2*HO2 + p];
    u64 pk = (((u64)__float_as_uint(v))<<32) | (u32)(HO2*HO2 - p);
    if (pk > best) best = pk;
  }
  int lane = tid & 63, w = tid >> 6;
  #pragma unroll
  for (int d=32; d; d>>=1){ u64 o = __shfl_down(best, d); if (o > best) best = o; }
  if (lane==0) red[w] = best;
  __syncthreads();
  if (tid==0){
    u64 bb = red[0];
    for (int q=1;q<4;q++) if (red[q] > bb) bb = red[q];
    int p = HO2*HO2 - (int)(bb & 0xffffffffu);
    sel_mp[b] = p;
    sel_score[b] = __uint_as_float((u32)(bb>>32));
    sel_nn[b] = loc[b*HO2*HO2 + p];
  }
}

// ---------------- d2(nn_sample[b], bank[m]) for all b,m (bf16 bank) ----------------
__device__ __forceinline__ void bf8dec(uint4 v, float* f){
  u32 a[4] = {v.x, v.y, v.z, v.w};
  #pragma unroll
  for (int q=0;q<4;q++){
    f[2*q]   = __uint_as_float(a[q]<<16);
    f[2*q+1] = __uint_as_float(a[q]&0xFFFF0000u);
  }
}

__global__ __launch_bounds__(256) void k_dbank(const ushort* __restrict__ bankB, const float* __restrict__ y2,
    const int* __restrict__ sel_nn, float* __restrict__ d_bank){
  int wave = threadIdx.x >> 6, lane = threadIdx.x & 63;
  int m = blockIdx.x*4 + wave;
  if (m >= NM) return;
  int nn[NB];
  #pragma unroll
  for (int b=0;b<NB;b++) nn[b] = sel_nn[b];
  const uint4* pm = (const uint4*)(bankB + (size_t)m*CC);
  float acc[NB];
  #pragma unroll
  for (int b=0;b<NB;b++) acc[b] = 0.f;
  #pragma unroll
  for (int it=0; it<3; ++it){
    uint4 v = pm[it*64 + lane];
    float vf[8]; bf8dec(v, vf);
    #pragma unroll
    for (int b=0;b<NB;b++){
      uint4 u = ((const uint4*)(bankB + (size_t)nn[b]*CC))[it*64 + lane];
      float uf[8]; bf8dec(u, uf);
      #pragma unroll
      for (int q=0;q<8;q++) acc[b] += vf[q]*uf[q];
    }
  }
  #pragma unroll
  for (int b=0;b<NB;b++){
    float s = warp_sum(acc[b]);
    if (lane==0) d_bank[(size_t)b*NM + m] = fmaxf(y2[nn[b]] + y2[m] - 2.f*s, 0.f);
  }
}

// ---------------- single-pass top-9 + anomaly score ----------------
__global__ __launch_bounds__(512) void k_score(const float* __restrict__ d_bank, const float* __restrict__ bank,
    const ushort* __restrict__ embB, const float* __restrict__ x2, const float* __restrict__ y2,
    const int* __restrict__ sel_mp, const float* __restrict__ sel_score, float* __restrict__ out_score){
  int b = blockIdx.x, tid = threadIdx.x;
  __shared__ u64 cand[512*NKNN];
  __shared__ int sel[NKNN];
  __shared__ u64 red[8];
  __shared__ u64 gbest_s;
  __shared__ float fred[8];
  __shared__ float sumexp_s;

  #pragma unroll
  for (int q=0;q<NKNN;q++) cand[tid*NKNN+q] = ~0ull;
  for (int m = tid; m < NM; m += 512){
    float v = d_bank[(size_t)b*NM + m];
    u64 pk = (((u64)__float_as_uint(v))<<32) | (u32)m;
    if (pk < cand[tid*NKNN + NKNN-1]){
      cand[tid*NKNN + NKNN-1] = pk;
      for (int q=NKNN-1; q>0 && cand[tid*NKNN+q] < cand[tid*NKNN+q-1]; --q){
        u64 t = cand[tid*NKNN+q]; cand[tid*NKNN+q] = cand[tid*NKNN+q-1]; cand[tid*NKNN+q-1] = t;
      }
    }
  }
  __syncthreads();
  int lane = tid & 63, w = tid >> 6;
  for (int k=0;k<NKNN;++k){
    u64 mybest = ~0ull;
    #pragma unroll
    for (int q=0;q<NKNN;q++){ u64 v = cand[tid*NKNN+q]; if (v < mybest) mybest = v; }
    u64 rb = mybest;
    #pragma unroll
    for (int d=32; d; d>>=1){ u64 o = __shfl_down(rb, d); if (o < rb) rb = o; }
    if (lane==0) red[w] = rb;
    __syncthreads();
    if (tid==0){
      u64 bb = red[0];
      for (int q=1;q<8;q++) if (red[q] < bb) bb = red[q];
      gbest_s = bb;
      sel[k] = (int)(bb & 0xffffffffu);
    }
    __syncthreads();
    u64 gb = gbest_s;
    #pragma unroll
    for (int q=0;q<NKNN;q++) if (cand[tid*NKNN+q] == gb) cand[tid*NKNN+q] = ~0ull;
    __syncthreads();
  }

  int mp = sel_mp[b];
  const ushort* fv = embB + (size_t)(b*HO2*HO2 + mp)*CC;
  float fx2 = x2[b*HO2*HO2 + mp];
  if (tid==0) sumexp_s = 0.f;
  __syncthreads();
  for (int k=0;k<NKNN;++k){
    const float* sv = bank + (size_t)sel[k]*CC;
    float part = 0.f;
    for (int i = tid; i < CC; i += 512) part += bf2f(fv[i])*sv[i];
    part = warp_sum(part);
    if (lane==0) fred[w] = part;
    __syncthreads();
    if (tid==0){
      float dot = 0.f;
      for (int q=0;q<8;q++) dot += fred[q];
      float d2 = fmaxf(fx2 + y2[sel[k]] - 2.f*dot, 0.f);
      sumexp_s += expf(sqrtf(d2));
    }
    __syncthreads();
  }
  if (tid==0){
    float s = sel_score[b];
    out_score[b] = (1.f - expf(s)/sumexp_s) * s;
  }
}

// ---------------- combined (blur ∘ bilinear) operator: T = G·R, 224x27 ----------------
__global__ void k_maketab(float* __restrict__ T, GW gw){
  int idx = blockIdx.x*256 + threadIdx.x;
  if (idx >= OH*HO2) return;
  int x = idx / HO2, j = idx - x*HO2;
  float s = 0.f;
  #pragma unroll
  for (int k=0;k<33;++k){
    int yy = x + k - 16;
    yy = (yy < 0) ? -yy : yy;
    yy = (yy > OH-1) ? (2*(OH-1) - yy) : yy;
    float fy = (yy + 0.5f) * (27.f/224.f) - 0.5f;
    int y0 = (int)floorf(fy); float wy = fy - (float)y0;
    int j0 = min(max(y0,0), HO2-1), j1 = min(max(y0+1,0), HO2-1);
    float c = ((j==j0)?(1.f-wy):0.f) + ((j==j1)?wy:0.f);
    s += gw.w[k]*c;
  }
  T[idx] = s;
}

// out_b = T · p_b · T^T  (one block per image)
__global__ __launch_bounds__(256) void k_amap_fused(const float* __restrict__ patch_d,
    const float* __restrict__ T, float* __restrict__ out){
  __shared__ float Ts[OH*HO2];
  __shared__ float ps[HO2*HO2];
  __shared__ float tmp[HO2*OH];
  int b = blockIdx.x, t = threadIdx.x;
  for (int idx=t; idx<OH*HO2; idx+=256) Ts[idx] = T[idx];
  for (int idx=t; idx<HO2*HO2; idx+=256) ps[idx] = patch_d[b*HO2*HO2+idx];
  __syncthreads();
  for (int idx=t; idx<HO2*OH; idx+=256){
    int i = idx/OH, x = idx - i*OH;
    float s = 0.f;
    #pragma unroll
    for (int j=0;j<HO2;j++) s += ps[i*HO2+j]*Ts[x*HO2+j];
    tmp[i*OH+x] = s;
  }
  __syncthreads();
  for (int idx=t; idx<OH*OH; idx+=256){
    int y = idx/OH, x = idx - y*OH;
    float s = 0.f;
    #pragma unroll
    for (int i=0;i<HO2;i++) s += Ts[y*HO2+i]*tmp[i*OH+x];
    out[(size_t)b*OH*OH + idx] = s;
  }
}

extern "C" void kernel_launch(void* const* d_in, const int* in_sizes, int n_in,
                              void* d_out, int out_size, void* d_ws, size_t ws_size,
                              hipStream_t stream){
  const float* f2   = (const float*)d_in[0];
  const float* f3   = (const float*)d_in[1];
  const float* bank = (const float*)d_in[2];
  float* out = (float*)d_out;

  char* ws = (char*)d_ws;
  size_t off = 0;
  auto alloc = [&](size_t bytes)->char*{ char* p = ws + off; off += (bytes + 255) & ~(size_t)255; return p; };
  ushort* embB    = (ushort*)alloc((size_t)NP*CC*2);
  ushort* bankB   = (ushort*)alloc((size_t)NM*CC*2);
  float* f3p      = (float*)alloc((size_t)NB*HO3*HO3*C3*4);
  float* y2       = (float*)alloc((size_t)NM*4);
  float* x2       = (float*)alloc((size_t)NP*4);
  u64*   packed   = (u64*)  alloc((size_t)NP*8);
  float* patch_d  = (float*)alloc((size_t)NP*4);
  int*   loc      = (int*)  alloc((size_t)NP*4);
  float* d_bank   = (float*)alloc((size_t)NB*NM*4);
  int*   sel_mp   = (int*)  alloc(NB*4);
  float* sel_scr  = (float*)alloc(NB*4);
  int*   sel_nn   = (int*)  alloc(NB*4);
  float* Tmat     = (float*)alloc((size_t)OH*HO2*4);

  GW gw;
  { float s=0.f; for(int i=0;i<33;i++){ float xx=(float)i-16.f; gw.w[i]=expf(-0.5f*(xx/4.f)*(xx/4.f)); s+=gw.w[i]; }
    for(int i=0;i<33;i++) gw.w[i]/=s; }

  k_avgpool2<<<NB*32,256,0,stream>>>(f2, embB);
  k_avgpool3<<<NB*16,256,0,stream>>>(f3, f3p);
  k_upsample3<<<(NB*HO2*HO2*C3+255)/256,256,0,stream>>>(f3p, embB);
  k_bank_prep<<<(NM+3)/4,256,0,stream>>>(bank, bankB, y2);
  k_rowsumsq_bf<<<(NP+3)/4,256,0,stream>>>(embB, x2, NP, packed);
  k_maketab<<<(OH*HO2+255)/256,256,0,stream>>>(Tmat, gw);
  k_distmin_mfma<<<NWG,512,0,stream>>>(embB, bankB, x2, y2, packed);
  k_unpack<<<(NP+255)/256,256,0,stream>>>(packed, patch_d, loc);
  k_argmax<<<NB,256,0,stream>>>(patch_d, loc, sel_mp, sel_scr, sel_nn);
  k_dbank<<<(NM+3)/4,256,0,stream>>>(bankB, y2, sel_nn, d_bank);
  k_score<<<NB,512,0,stream>>>(d_bank, bank, embB, x2, y2, sel_mp, sel_scr, out + AMAP_N);
  k_amap_fused<<<NB,256,0,stream>>>(patch_d, Tmat, out);
}

// Round 8
// 938.679 us; speedup vs baseline: 1.9005x; 1.9005x over previous
//
#include <hip/hip_runtime.h>
#include <math.h>

#define NB 8
#define C2 512
#define C3 1024
#define HIN2 28
#define HIN3 14
#define HO2 27
#define HO3 13
#define CC 1536
#define NP (NB*HO2*HO2)   /* 5832 */
#define NM 32000
#define NKNN 9
#define OH 224
#define AMAP_N (NB*OH*OH) /* 401408 */

/* 256x256 tile GEMM geometry */
#define BM 256
#define BN 256
#define BK 64
#define KT (CC/BK)        /* 24 */
#define MB_CNT ((NP+BM-1)/BM)   /* 23 */
#define NB_CNT (NM/BN)          /* 125 */
#define NWG (MB_CNT*NB_CNT)     /* 2875 */

typedef unsigned long long u64;
typedef unsigned int u32;
typedef __attribute__((ext_vector_type(8))) short bf16x8;
typedef __attribute__((ext_vector_type(4))) float f32x4;

struct GW { float w[33]; };

__device__ __forceinline__ float warp_sum(float v){
  #pragma unroll
  for (int off=32; off; off>>=1) v += __shfl_down(v, off);
  return v;
}

__device__ __forceinline__ ushort f2bf(float f){
  u32 u = __float_as_uint(f);
  u32 r = (u + 0x7FFFu + ((u>>16)&1u)) >> 16;
  return (ushort)r;
}
__device__ __forceinline__ float bf2f(ushort b){
  return __uint_as_float(((u32)b)<<16);
}

#define GLDS(g, l) __builtin_amdgcn_global_load_lds((const __attribute__((address_space(1))) void*)(g), (__attribute__((address_space(3))) void*)(l), 16, 0, 0)
#define WAITVM2() asm volatile("s_waitcnt vmcnt(2)" ::: "memory")
#define WAITVM0() asm volatile("s_waitcnt vmcnt(0)" ::: "memory")
#define SB0() __builtin_amdgcn_sched_barrier(0)
__device__ __forceinline__ void bar_raw(){
  asm volatile("" ::: "memory");
  __builtin_amdgcn_s_barrier();
  asm volatile("" ::: "memory");
}

// ---------------- avg pool k=4,s=1,p=1 (LDS-tiled transpose), write bf16 emb ----------------
__global__ __launch_bounds__(256) void k_avgpool2(const float* __restrict__ in, ushort* __restrict__ embB){
  __shared__ float pl[16*789];
  int b = blockIdx.x >> 5, cg = blockIdx.x & 31;
  const float4* src = (const float4*)(in + ((size_t)b*C2 + cg*16)*(HIN2*HIN2));
  for (int idx = threadIdx.x; idx < 16*196; idx += 256){
    int c = idx/196, p4 = idx - c*196;
    float4 v = src[idx];
    float* d = &pl[c*789 + p4*4];
    d[0]=v.x; d[1]=v.y; d[2]=v.z; d[3]=v.w;
  }
  __syncthreads();
  int c = threadIdx.x & 15, g = threadIdx.x >> 4;
  for (int pos = g; pos < HO2*HO2; pos += 16){
    int i = pos/HO2, j = pos - i*HO2;
    const float* p = &pl[c*789];
    float s = 0.f;
    #pragma unroll
    for (int di=0; di<4; ++di){
      int y = i - 1 + di;
      if ((unsigned)y >= HIN2) continue;
      #pragma unroll
      for (int dj=0; dj<4; ++dj){
        int x = j - 1 + dj;
        if ((unsigned)x < HIN2) s += p[y*HIN2 + x];
      }
    }
    embB[((size_t)((b*HO2 + i)*HO2 + j))*CC + cg*16 + c] = f2bf(s * (1.f/16.f));
  }
}

__global__ __launch_bounds__(256) void k_avgpool3(const float* __restrict__ in, float* __restrict__ f3p){
  __shared__ float pl[64*197];
  int b = blockIdx.x >> 4, cg = blockIdx.x & 15;
  const float4* src = (const float4*)(in + ((size_t)b*C3 + cg*64)*(HIN3*HIN3));
  for (int idx = threadIdx.x; idx < 64*49; idx += 256){
    int c = idx/49, p4 = idx - c*49;
    float4 v = src[idx];
    float* d = &pl[c*197 + p4*4];
    d[0]=v.x; d[1]=v.y; d[2]=v.z; d[3]=v.w;
  }
  __syncthreads();
  int c = threadIdx.x & 63, g = threadIdx.x >> 6;
  for (int pos = g; pos < HO3*HO3; pos += 4){
    int i = pos/HO3, j = pos - i*HO3;
    const float* p = &pl[c*197];
    float s = 0.f;
    #pragma unroll
    for (int di=0; di<4; ++di){
      int y = i - 1 + di;
      if ((unsigned)y >= HIN3) continue;
      #pragma unroll
      for (int dj=0; dj<4; ++dj){
        int x = j - 1 + dj;
        if ((unsigned)x < HIN3) s += p[y*HIN3 + x];
      }
    }
    f3p[((size_t)((b*HO3 + i)*HO3 + j))*C3 + cg*64 + c] = s * (1.f/16.f);
  }
}

// ---------------- bilinear 13x13 -> 27x27 (half-pixel, clamp), write bf16 ----------------
__global__ void k_upsample3(const float* __restrict__ f3p, ushort* __restrict__ embB){
  int t = blockIdx.x*256 + threadIdx.x;
  if (t >= NB*HO2*HO2*C3) return;
  int c = t % C3; int r = t / C3;
  int ox = r % HO2; r /= HO2;
  int oy = r % HO2; int b = r / HO2;
  float fy = (oy + 0.5f) * (13.f/27.f) - 0.5f;
  float fx = (ox + 0.5f) * (13.f/27.f) - 0.5f;
  int y0 = (int)floorf(fy); float wy = fy - (float)y0;
  int x0 = (int)floorf(fx); float wx = fx - (float)x0;
  int y0c = min(max(y0,0), HO3-1), y1c = min(max(y0+1,0), HO3-1);
  int x0c = min(max(x0,0), HO3-1), x1c = min(max(x0+1,0), HO3-1);
  const float* base = f3p + (size_t)(b*HO3*HO3)*C3;
  float v00 = base[(size_t)(y0c*HO3 + x0c)*C3 + c];
  float v01 = base[(size_t)(y0c*HO3 + x1c)*C3 + c];
  float v10 = base[(size_t)(y1c*HO3 + x0c)*C3 + c];
  float v11 = base[(size_t)(y1c*HO3 + x1c)*C3 + c];
  float v = (1.f-wy)*((1.f-wx)*v00 + wx*v01) + wy*((1.f-wx)*v10 + wx*v11);
  embB[((size_t)((b*HO2 + oy)*HO2 + ox))*CC + C2 + c] = f2bf(v);
}

// ---------------- fused bank fp32->bf16 convert + row sum of squares ----------------
__global__ void k_bank_prep(const float* __restrict__ bank, ushort* __restrict__ bankB,
                            float* __restrict__ y2){
  int wave = threadIdx.x >> 6, lane = threadIdx.x & 63;
  int r = blockIdx.x*4 + wave;
  if (r >= NM) return;
  const float4* p = (const float4*)(bank + (size_t)r*CC);
  ushort4* q = (ushort4*)(bankB + (size_t)r*CC);
  float s = 0.f;
  #pragma unroll
  for (int it=0; it<6; ++it){
    float4 v = p[it*64 + lane];
    s += v.x*v.x + v.y*v.y + v.z*v.z + v.w*v.w;
    ushort4 o; o.x = f2bf(v.x); o.y = f2bf(v.y); o.z = f2bf(v.z); o.w = f2bf(v.w);
    q[it*64 + lane] = o;
  }
  s = warp_sum(s);
  if (lane==0) y2[r] = s;
}

// also initializes packed[] (rows == NP)
__global__ void k_rowsumsq_bf(const ushort* __restrict__ src, float* __restrict__ dst, int rows,
                              u64* __restrict__ packed){
  int wave = threadIdx.x >> 6;
  int lane = threadIdx.x & 63;
  int r = blockIdx.x*4 + wave;
  if (r >= rows) return;
  const uint4* p = (const uint4*)(src + (size_t)r*CC);
  float s = 0.f;
  #pragma unroll
  for (int it=0; it<3; ++it){
    uint4 v = p[it*64 + lane];
    u32 ws_[4] = {v.x, v.y, v.z, v.w};
    #pragma unroll
    for (int q=0;q<4;q++){
      float lo = __uint_as_float(ws_[q]<<16);
      float hi = __uint_as_float(ws_[q]&0xFFFF0000u);
      s += lo*lo + hi*hi;
    }
  }
  s = warp_sum(s);
  if (lane==0){ dst[r] = s; packed[r] = ~0ull; }
}

// ---------------- fused bf16 MFMA distance GEMM + min/argmin ----------------
// R5 schedule (best measured: 598us, MfmaUtil 43%): 256x256 tile, BK=64, 8 waves
// (2Mx4N), double-buffered LDS, XOR-swizzle (T2). 4 phases per K-tile; each phase:
// {vmcnt(2)+barrier, 2 global_load_lds (quarter of next tile), ds_read a FUTURE
// cluster's frags, setprio-wrapped 16 MFMA}. Per-wave load order A-lo,B-lo,B-hi,A-hi
// makes the uniform vmcnt(2) retire exactly the half-tile the phase reads.
// Read-ahead (no barrier between a wave's reads and another's MFMAs) lets waves
// drift so LDS reads overlap other waves' MFMA clusters -- the lockstep variant
// (R6) and A-direct (R7) both measured worse.
__global__ __launch_bounds__(512, 2) void k_distmin_mfma(
    const ushort* __restrict__ A, const ushort* __restrict__ B,
    const float* __restrict__ x2, const float* __restrict__ y2,
    u64* __restrict__ packed)
{
  __shared__ ushort smem[4*BM*BK];   // [A0 | B0 | A1 | B1] = 128KB
  ushort* As0 = smem;
  ushort* Bs0 = smem + BM*BK;
  ushort* As1 = smem + 2*BM*BK;
  ushort* Bs1 = smem + 3*BM*BK;

  const int tid = threadIdx.x;
  const int w   = tid >> 6;          // wave 0..7
  const int l   = tid & 63;
  const int wr  = w >> 2;            // 0..1  (M: wr*128)
  const int wc  = w & 3;             // 0..3  (N: wc*64)
  const int ccol = l & 15;
  const int cgrp = l >> 4;

  // bijective XCD swizzle (m204): nwg=2875
  int orig = blockIdx.x;
  const int q8 = NWG/8, r8 = NWG%8;
  int xcd = orig & 7, sidx = orig >> 3;
  int wg = (xcd < r8 ? xcd*(q8+1) : r8*(q8+1) + (xcd-r8)*q8) + sidx;
  const int mb = wg % MB_CNT;        // M fastest: consecutive wgs share B-panel
  const int nb = wg / MB_CNT;
  const int m0 = mb * BM;
  const int n0 = nb * BN;

  // Staging chunks (8 rows x 64 cols = 1KB each, 32 per matrix); half-tile groups:
  //  A-lo: chunks 0-7,16-23 -> rAlo (mi 0-3);  A-hi: +8 -> rAhi (mi 4-7)
  //  B-lo: chunks {0-3 mod 8} -> rBlo (ni 0-1); B-hi: +4 -> rBhi (ni 2-3)
  const int rowin = l >> 3;
  const int scol  = (((l&7) ^ rowin) * 8);     // swizzled source segment (T2)
  int chA1[2], chA2[2], chB1[2], chB2[2];
  u32 aO1[2], aO2[2], bO1[2], bO2[2];
  u32 lA1[2], lA2[2], lB1[2], lB2[2];
  #pragma unroll
  for (int c=0;c<2;c++){
    chA1[c] = (w<4) ? (2*w+c) : (8+2*w+c);
    chA2[c] = chA1[c] + 8;
    chB1[c] = (w>>1)*8 + (w&1)*2 + c;
    chB2[c] = chB1[c] + 4;
    aO1[c] = (u32)min(m0 + chA1[c]*8 + rowin, NP-1)*CC + scol;
    aO2[c] = (u32)min(m0 + chA2[c]*8 + rowin, NP-1)*CC + scol;
    bO1[c] = (u32)(n0 + chB1[c]*8 + rowin)*CC + scol;
    bO2[c] = (u32)(n0 + chB2[c]*8 + rowin)*CC + scol;
    lA1[c] = (u32)chA1[c]*1024 + l*16;
    lA2[c] = (u32)chA2[c]*1024 + l*16;
    lB1[c] = (u32)chB1[c]*1024 + l*16;
    lB2[c] = (u32)chB2[c]*1024 + l*16;
  }

  const u32 o0 = (u32)((cgrp ^ (ccol & 7)) * 8);
  u32 aRow[8], bRow[4];
  #pragma unroll
  for (int mi=0;mi<8;mi++) aRow[mi] = (u32)(wr*128 + mi*16 + ccol)*BK;
  #pragma unroll
  for (int ni=0;ni<4;ni++) bRow[ni] = (u32)(wc*64 + ni*16 + ccol)*BK;

  f32x4 acc[8][4];
  #pragma unroll
  for (int mi=0;mi<8;mi++)
    #pragma unroll
    for (int ni=0;ni<4;ni++)
      acc[mi][ni] = (f32x4){0.f,0.f,0.f,0.f};

  bf16x8 rAlo[4][2], rAhi[4][2], rBlo[2][2], rBhi[2][2];

  // -------- prologue: tile 0 --------
  #pragma unroll
  for (int c=0;c<2;c++) GLDS(A + aO1[c], (char*)As0 + lA1[c]);
  #pragma unroll
  for (int c=0;c<2;c++) GLDS(B + bO1[c], (char*)Bs0 + lB1[c]);
  WAITVM0(); bar_raw();
  #pragma unroll
  for (int mi=0;mi<4;mi++)
    #pragma unroll
    for (int ks=0;ks<2;ks++)
      rAlo[mi][ks] = *(const bf16x8*)&As0[aRow[mi] + (o0 ^ (u32)(ks<<5))];
  #pragma unroll
  for (int ni=0;ni<2;ni++)
    #pragma unroll
    for (int ks=0;ks<2;ks++)
      rBlo[ni][ks] = *(const bf16x8*)&Bs0[bRow[ni] + (o0 ^ (u32)(ks<<5))];
  #pragma unroll
  for (int c=0;c<2;c++) GLDS(B + bO2[c], (char*)Bs0 + lB2[c]);
  #pragma unroll
  for (int c=0;c<2;c++) GLDS(A + aO2[c], (char*)As0 + lA2[c]);
  // outstanding: [B-hi(0) x2, A-hi(0) x2]

  const ushort* cA = As0; const ushort* cB = Bs0;
  ushort* nA = As1; ushort* nB = Bs1;

  #pragma unroll 1
  for (int kt=0; kt<KT; ++kt){
    const u32 kk = (u32)(kt+1)*BK;   // tail garbage stays inside d_ws

    // ---- P0: Q00 (rAlo x rBlo); read rBhi(cur); stage A-lo(next)
    WAITVM2(); bar_raw(); SB0();
    GLDS(A + aO1[0] + kk, (char*)nA + lA1[0]);
    GLDS(A + aO1[1] + kk, (char*)nA + lA1[1]);
    #pragma unroll
    for (int ni=0;ni<2;ni++)
      #pragma unroll
      for (int ks=0;ks<2;ks++)
        rBhi[ni][ks] = *(const bf16x8*)&cB[bRow[ni+2] + (o0 ^ (u32)(ks<<5))];
    __builtin_amdgcn_s_setprio(1);
    #pragma unroll
    for (int mi=0;mi<4;mi++)
      #pragma unroll
      for (int ni=0;ni<2;ni++)
        #pragma unroll
        for (int ks=0;ks<2;ks++)
          acc[mi][ni] = __builtin_amdgcn_mfma_f32_16x16x32_bf16(rAlo[mi][ks], rBlo[ni][ks], acc[mi][ni], 0, 0, 0);
    __builtin_amdgcn_s_setprio(0);

    // ---- P1: Q01 (rAlo x rBhi); read rAhi(cur); stage B-lo(next)
    WAITVM2(); bar_raw(); SB0();
    GLDS(B + bO1[0] + kk, (char*)nB + lB1[0]);
    GLDS(B + bO1[1] + kk, (char*)nB + lB1[1]);
    #pragma unroll
    for (int mi=0;mi<4;mi++)
      #pragma unroll
      for (int ks=0;ks<2;ks++)
        rAhi[mi][ks] = *(const bf16x8*)&cA[aRow[mi+4] + (o0 ^ (u32)(ks<<5))];
    __builtin_amdgcn_s_setprio(1);
    #pragma unroll
    for (int mi=0;mi<4;mi++)
      #pragma unroll
      for (int ni=0;ni<2;ni++)
        #pragma unroll
        for (int ks=0;ks<2;ks++)
          acc[mi][ni+2] = __builtin_amdgcn_mfma_f32_16x16x32_bf16(rAlo[mi][ks], rBhi[ni][ks], acc[mi][ni+2], 0, 0, 0);
    __builtin_amdgcn_s_setprio(0);

    // ---- P2: Q10 (rAhi x rBlo); read rAlo(NEXT); stage B-hi(next)
    WAITVM2(); bar_raw(); SB0();
    GLDS(B + bO2[0] + kk, (char*)nB + lB2[0]);
    GLDS(B + bO2[1] + kk, (char*)nB + lB2[1]);
    #pragma unroll
    for (int mi=0;mi<4;mi++)
      #pragma unroll
      for (int ks=0;ks<2;ks++)
        rAlo[mi][ks] = *(const bf16x8*)&((const ushort*)nA)[aRow[mi] + (o0 ^ (u32)(ks<<5))];
    __builtin_amdgcn_s_setprio(1);
    #pragma unroll
    for (int mi=0;mi<4;mi++)
      #pragma unroll
      for (int ni=0;ni<2;ni++)
        #pragma unroll
        for (int ks=0;ks<2;ks++)
          acc[mi+4][ni] = __builtin_amdgcn_mfma_f32_16x16x32_bf16(rAhi[mi][ks], rBlo[ni][ks], acc[mi+4][ni], 0, 0, 0);
    __builtin_amdgcn_s_setprio(0);

    // ---- P3: Q11 (rAhi x rBhi); read rBlo(NEXT); stage A-hi(next)
    WAITVM2(); bar_raw(); SB0();
    GLDS(A + aO2[0] + kk, (char*)nA + lA2[0]);
    GLDS(A + aO2[1] + kk, (char*)nA + lA2[1]);
    #pragma unroll
    for (int ni=0;ni<2;ni++)
      #pragma unroll
      for (int ks=0;ks<2;ks++)
        rBlo[ni][ks] = *(const bf16x8*)&((const ushort*)nB)[bRow[ni] + (o0 ^ (u32)(ks<<5))];
    __builtin_amdgcn_s_setprio(1);
    #pragma unroll
    for (int mi=0;mi<4;mi++)
      #pragma unroll
      for (int ni=0;ni<2;ni++)
        #pragma unroll
        for (int ks=0;ks<2;ks++)
          acc[mi+4][ni+2] = __builtin_amdgcn_mfma_f32_16x16x32_bf16(rAhi[mi][ks], rBhi[ni][ks], acc[mi+4][ni+2], 0, 0, 0);
    __builtin_amdgcn_s_setprio(0);

    // swap buffers
    ushort* t1 = (ushort*)cA; cA = nA; nA = t1;
    ushort* t2 = (ushort*)cB; cB = nB; nB = t2;
  }
  WAITVM0();   // drain tail garbage loads before LDS goes away

  // epilogue: d2 = x2 + y2 - 2*dot ; min over this block's 256 columns, then atomicMin
  float xv[8][4];
  #pragma unroll
  for (int mi=0;mi<8;mi++)
    #pragma unroll
    for (int r=0;r<4;r++)
      xv[mi][r] = x2[min(m0 + wr*128 + mi*16 + cgrp*4 + r, NP-1)];

  u64 best[8][4];
  #pragma unroll
  for (int mi=0;mi<8;mi++)
    #pragma unroll
    for (int r=0;r<4;r++) best[mi][r] = ~0ull;

  #pragma unroll
  for (int ni=0;ni<4;ni++){
    const int n = n0 + wc*64 + ni*16 + ccol;
    const float yy = y2[n];
    #pragma unroll
    for (int mi=0;mi<8;mi++)
      #pragma unroll
      for (int r=0;r<4;r++){
        float d2 = fmaxf(xv[mi][r] + yy - 2.f*acc[mi][ni][r], 0.f);
        u64 pk = (((u64)__float_as_uint(d2))<<32) | (u32)n;
        if (pk < best[mi][r]) best[mi][r] = pk;
      }
  }

  #pragma unroll
  for (int mi=0;mi<8;mi++)
    #pragma unroll
    for (int r=0;r<4;r++){
      u64 pk = best[mi][r];
      #pragma unroll
      for (int md=1; md<16; md<<=1){
        u64 o = __shfl_xor(pk, md);
        if (o < pk) pk = o;
      }
      const int row = m0 + wr*128 + mi*16 + cgrp*4 + r;
      if (ccol==0 && row < NP) atomicMin(&packed[row], pk);
    }
}

__global__ void k_unpack(const u64* __restrict__ packed, float* __restrict__ patch_d, int* __restrict__ loc){
  int t = blockIdx.x*256 + threadIdx.x;
  if (t < NP){
    u64 v = packed[t];
    patch_d[t] = sqrtf(__uint_as_float((u32)(v>>32)));
    loc[t] = (int)(v & 0xffffffffu);
  }
}

// ---------------- per-batch argmax of patch scores ----------------
__global__ void k_argmax(const float* __restrict__ patch_d, const int* __restrict__ loc,
                         int* __restrict__ sel_mp, float* __restrict__ sel_score, int* __restrict__ sel_nn){
  int b = blockIdx.x;
  int tid = threadIdx.x;
  __shared__ u64 red[4];
  u64 best = 0;
  for (int p = tid; p < HO2*HO2; p += 256){
    float v = patch_d[b*HO2*HO2 + p];
    u64 pk = (((u64)__float_as_uint(v))<<32) | (u32)(HO2*HO2 - p);
    if (pk > best) best = pk;
  }
  int lane = tid & 63, w = tid >> 6;
  #pragma unroll
  for (int d=32; d; d>>=1){ u64 o = __shfl_down(best, d); if (o > best) best = o; }
  if (lane==0) red[w] = best;
  __syncthreads();
  if (tid==0){
    u64 bb = red[0];
    for (int q=1;q<4;q++) if (red[q] > bb) bb = red[q];
    int p = HO2*HO2 - (int)(bb & 0xffffffffu);
    sel_mp[b] = p;
    sel_score[b] = __uint_as_float((u32)(bb>>32));
    sel_nn[b] = loc[b*HO2*HO2 + p];
  }
}

// ---------------- d2(nn_sample[b], bank[m]) for all b,m (bf16 bank) ----------------
__device__ __forceinline__ void bf8dec(uint4 v, float* f){
  u32 a[4] = {v.x, v.y, v.z, v.w};
  #pragma unroll
  for (int q=0;q<4;q++){
    f[2*q]   = __uint_as_float(a[q]<<16);
    f[2*q+1] = __uint_as_float(a[q]&0xFFFF0000u);
  }
}

__global__ __launch_bounds__(256) void k_dbank(const ushort* __restrict__ bankB, const float* __restrict__ y2,
    const int* __restrict__ sel_nn, float* __restrict__ d_bank){
  int wave = threadIdx.x >> 6, lane = threadIdx.x & 63;
  int m = blockIdx.x*4 + wave;
  if (m >= NM) return;
  int nn[NB];
  #pragma unroll
  for (int b=0;b<NB;b++) nn[b] = sel_nn[b];
  const uint4* pm = (const uint4*)(bankB + (size_t)m*CC);
  float acc[NB];
  #pragma unroll
  for (int b=0;b<NB;b++) acc[b] = 0.f;
  #pragma unroll
  for (int it=0; it<3; ++it){
    uint4 v = pm[it*64 + lane];
    float vf[8]; bf8dec(v, vf);
    #pragma unroll
    for (int b=0;b<NB;b++){
      uint4 u = ((const uint4*)(bankB + (size_t)nn[b]*CC))[it*64 + lane];
      float uf[8]; bf8dec(u, uf);
      #pragma unroll
      for (int q=0;q<8;q++) acc[b] += vf[q]*uf[q];
    }
  }
  #pragma unroll
  for (int b=0;b<NB;b++){
    float s = warp_sum(acc[b]);
    if (lane==0) d_bank[(size_t)b*NM + m] = fmaxf(y2[nn[b]] + y2[m] - 2.f*s, 0.f);
  }
}

// ---------------- single-pass top-9 + anomaly score ----------------
__global__ __launch_bounds__(512) void k_score(const float* __restrict__ d_bank, const float* __restrict__ bank,
    const ushort* __restrict__ embB, const float* __restrict__ x2, const float* __restrict__ y2,
    const int* __restrict__ sel_mp, const float* __restrict__ sel_score, float* __restrict__ out_score){
  int b = blockIdx.x, tid = threadIdx.x;
  __shared__ u64 cand[512*NKNN];
  __shared__ int sel[NKNN];
  __shared__ u64 red[8];
  __shared__ u64 gbest_s;
  __shared__ float fred[8];
  __shared__ float sumexp_s;

  #pragma unroll
  for (int q=0;q<NKNN;q++) cand[tid*NKNN+q] = ~0ull;
  for (int m = tid; m < NM; m += 512){
    float v = d_bank[(size_t)b*NM + m];
    u64 pk = (((u64)__float_as_uint(v))<<32) | (u32)m;
    if (pk < cand[tid*NKNN + NKNN-1]){
      cand[tid*NKNN + NKNN-1] = pk;
      for (int q=NKNN-1; q>0 && cand[tid*NKNN+q] < cand[tid*NKNN+q-1]; --q){
        u64 t = cand[tid*NKNN+q]; cand[tid*NKNN+q] = cand[tid*NKNN+q-1]; cand[tid*NKNN+q-1] = t;
      }
    }
  }
  __syncthreads();
  int lane = tid & 63, w = tid >> 6;
  for (int k=0;k<NKNN;++k){
    u64 mybest = ~0ull;
    #pragma unroll
    for (int q=0;q<NKNN;q++){ u64 v = cand[tid*NKNN+q]; if (v < mybest) mybest = v; }
    u64 rb = mybest;
    #pragma unroll
    for (int d=32; d; d>>=1){ u64 o = __shfl_down(rb, d); if (o < rb) rb = o; }
    if (lane==0) red[w] = rb;
    __syncthreads();
    if (tid==0){
      u64 bb = red[0];
      for (int q=1;q<8;q++) if (red[q] < bb) bb = red[q];
      gbest_s = bb;
      sel[k] = (int)(bb & 0xffffffffu);
    }
    __syncthreads();
    u64 gb = gbest_s;
    #pragma unroll
    for (int q=0;q<NKNN;q++) if (cand[tid*NKNN+q] == gb) cand[tid*NKNN+q] = ~0ull;
    __syncthreads();
  }

  int mp = sel_mp[b];
  const ushort* fv = embB + (size_t)(b*HO2*HO2 + mp)*CC;
  float fx2 = x2[b*HO2*HO2 + mp];
  if (tid==0) sumexp_s = 0.f;
  __syncthreads();
  for (int k=0;k<NKNN;++k){
    const float* sv = bank + (size_t)sel[k]*CC;
    float part = 0.f;
    for (int i = tid; i < CC; i += 512) part += bf2f(fv[i])*sv[i];
    part = warp_sum(part);
    if (lane==0) fred[w] = part;
    __syncthreads();
    if (tid==0){
      float dot = 0.f;
      for (int q=0;q<8;q++) dot += fred[q];
      float d2 = fmaxf(fx2 + y2[sel[k]] - 2.f*dot, 0.f);
      sumexp_s += expf(sqrtf(d2));
    }
    __syncthreads();
  }
  if (tid==0){
    float s = sel_score[b];
    out_score[b] = (1.f - expf(s)/sumexp_s) * s;
  }
}

// ---------------- combined (blur ∘ bilinear) operator: T = G·R, 224x27 ----------------
__global__ void k_maketab(float* __restrict__ T, GW gw){
  int idx = blockIdx.x*256 + threadIdx.x;
  if (idx >= OH*HO2) return;
  int x = idx / HO2, j = idx - x*HO2;
  float s = 0.f;
  #pragma unroll
  for (int k=0;k<33;++k){
    int yy = x + k - 16;
    yy = (yy < 0) ? -yy : yy;
    yy = (yy > OH-1) ? (2*(OH-1) - yy) : yy;
    float fy = (yy + 0.5f) * (27.f/224.f) - 0.5f;
    int y0 = (int)floorf(fy); float wy = fy - (float)y0;
    int j0 = min(max(y0,0), HO2-1), j1 = min(max(y0+1,0), HO2-1);
    float c = ((j==j0)?(1.f-wy):0.f) + ((j==j1)?wy:0.f);
    s += gw.w[k]*c;
  }
  T[idx] = s;
}

// out_b = T · p_b · T^T  (one block per image)
__global__ __launch_bounds__(256) void k_amap_fused(const float* __restrict__ patch_d,
    const float* __restrict__ T, float* __restrict__ out){
  __shared__ float Ts[OH*HO2];
  __shared__ float ps[HO2*HO2];
  __shared__ float tmp[HO2*OH];
  int b = blockIdx.x, t = threadIdx.x;
  for (int idx=t; idx<OH*HO2; idx+=256) Ts[idx] = T[idx];
  for (int idx=t; idx<HO2*HO2; idx+=256) ps[idx] = patch_d[b*HO2*HO2+idx];
  __syncthreads();
  for (int idx=t; idx<HO2*OH; idx+=256){
    int i = idx/OH, x = idx - i*OH;
    float s = 0.f;
    #pragma unroll
    for (int j=0;j<HO2;j++) s += ps[i*HO2+j]*Ts[x*HO2+j];
    tmp[i*OH+x] = s;
  }
  __syncthreads();
  for (int idx=t; idx<OH*OH; idx+=256){
    int y = idx/OH, x = idx - y*OH;
    float s = 0.f;
    #pragma unroll
    for (int i=0;i<HO2;i++) s += Ts[y*HO2+i]*tmp[i*OH+x];
    out[(size_t)b*OH*OH + idx] = s;
  }
}

extern "C" void kernel_launch(void* const* d_in, const int* in_sizes, int n_in,
                              void* d_out, int out_size, void* d_ws, size_t ws_size,
                              hipStream_t stream){
  const float* f2   = (const float*)d_in[0];
  const float* f3   = (const float*)d_in[1];
  const float* bank = (const float*)d_in[2];
  float* out = (float*)d_out;

  char* ws = (char*)d_ws;
  size_t off = 0;
  auto alloc = [&](size_t bytes)->char*{ char* p = ws + off; off += (bytes + 255) & ~(size_t)255; return p; };
  ushort* embB    = (ushort*)alloc((size_t)NP*CC*2);
  ushort* bankB   = (ushort*)alloc((size_t)NM*CC*2);
  float* f3p      = (float*)alloc((size_t)NB*HO3*HO3*C3*4);
  float* y2       = (float*)alloc((size_t)NM*4);
  float* x2       = (float*)alloc((size_t)NP*4);
  u64*   packed   = (u64*)  alloc((size_t)NP*8);
  float* patch_d  = (float*)alloc((size_t)NP*4);
  int*   loc      = (int*)  alloc((size_t)NP*4);
  float* d_bank   = (float*)alloc((size_t)NB*NM*4);
  int*   sel_mp   = (int*)  alloc(NB*4);
  float* sel_scr  = (float*)alloc(NB*4);
  int*   sel_nn   = (int*)  alloc(NB*4);
  float* Tmat     = (float*)alloc((size_t)OH*HO2*4);

  GW gw;
  { float s=0.f; for(int i=0;i<33;i++){ float xx=(float)i-16.f; gw.w[i]=expf(-0.5f*(xx/4.f)*(xx/4.f)); s+=gw.w[i]; }
    for(int i=0;i<33;i++) gw.w[i]/=s; }

  k_avgpool2<<<NB*32,256,0,stream>>>(f2, embB);
  k_avgpool3<<<NB*16,256,0,stream>>>(f3, f3p);
  k_upsample3<<<(NB*HO2*HO2*C3+255)/256,256,0,stream>>>(f3p, embB);
  k_bank_prep<<<(NM+3)/4,256,0,stream>>>(bank, bankB, y2);
  k_rowsumsq_bf<<<(NP+3)/4,256,0,stream>>>(embB, x2, NP, packed);
  k_maketab<<<(OH*HO2+255)/256,256,0,stream>>>(Tmat, gw);
  k_distmin_mfma<<<NWG,512,0,stream>>>(embB, bankB, x2, y2, packed);
  k_unpack<<<(NP+255)/256,256,0,stream>>>(packed, patch_d, loc);
  k_argmax<<<NB,256,0,stream>>>(patch_d, loc, sel_mp, sel_scr, sel_nn);
  k_dbank<<<(NM+3)/4,256,0,stream>>>(bankB, y2, sel_nn, d_bank);
  k_score<<<NB,512,0,stream>>>(d_bank, bank, embB, x2, y2, sel_mp, sel_scr, out + AMAP_N);
  k_amap_fused<<<NB,256,0,stream>>>(patch_d, Tmat, out);
}